// Round 2
// baseline (176.759 us; speedup 1.0000x reference)
//
#include <hip/hip_runtime.h>
#include <hip/hip_bf16.h>

// Problem constants
#define B_   256
#define C_   256
#define CH_  128
#define N_   196           // H*W = 14*14
#define NF4  49            // float4s per (b,c) row
#define ROWS (B_ * C_)     // 65536
#define YSUM_BLKS (ROWS / 4)          // 16384 (4 waves per block, wave per row)
#define QF4  (64 * NF4)               // 3136 float4 per (batch, 64-channel quarter)
#define EPS 1e-5f

// ---------------------------------------------------------------------------
// Kernel A — two independent jobs in one dispatch (disjoint block ranges):
//   blocks [0, 16384):     Ysum[b,c] = sum_n y[b,c,n], wave-per-row
//   blocks [16384, 16640): WzvT[c][o] = sum_k Wz[o,k] * Wv[k,c]
// No ordering needed between the two jobs; both only feed Kernel B.
// ---------------------------------------------------------------------------
__global__ __launch_bounds__(256) void k_pre(const float* __restrict__ y,
                                             const float* __restrict__ Wz,
                                             const float* __restrict__ Wv,
                                             float* __restrict__ ysum,
                                             float* __restrict__ WzvT) {
    int bid = blockIdx.x;
    if (bid < YSUM_BLKS) {
        // --- Ysum: 4 waves per block, one 196-float row per wave ---
        int wave = bid * 4 + (threadIdx.x >> 6);
        int lane = threadIdx.x & 63;
        const float4* row = (const float4*)(y + (size_t)wave * N_);
        float s = 0.f;
        if (lane < NF4) {
            float4 v = row[lane];
            s = (v.x + v.y) + (v.z + v.w);
        }
        #pragma unroll
        for (int off = 32; off > 0; off >>= 1)
            s += __shfl_down(s, off, 64);
        if (lane == 0) ysum[wave] = s;
    } else {
        // --- WzvT: block per c, thread per o, Wv column staged in LDS ---
        __shared__ float sWv[CH_];
        int c = bid - YSUM_BLKS;         // 0..255
        int o = threadIdx.x;             // 0..255
        if (o < CH_) sWv[o] = Wv[o * C_ + c];
        __syncthreads();
        const float4* wzrow = (const float4*)(Wz + o * CH_);
        float acc = 0.f;
        #pragma unroll
        for (int k4 = 0; k4 < CH_ / 4; k4++) {
            float4 w = wzrow[k4];
            acc += w.x * sWv[4 * k4 + 0];
            acc += w.y * sWv[4 * k4 + 1];
            acc += w.z * sWv[4 * k4 + 2];
            acc += w.w * sWv[4 * k4 + 3];
        }
        WzvT[c * C_ + o] = acc;
    }
}

// ---------------------------------------------------------------------------
// Kernel B — block per (batch b, quarter q). Quarter q covers channels
// [64q, 64q+64) exactly (3136 float4 = 64*49). Phase 1: Ysum[b,:] -> LDS.
// Phase 2: Zs for the 64 channels (4 threads/channel over k, LDS reduce,
// BN affine folded in). Phase 3: stream out = x + Zs[channel], float4.
// ---------------------------------------------------------------------------
__global__ __launch_bounds__(256) void k_post(const float* __restrict__ x,
                                              const float* __restrict__ ysum,
                                              const float* __restrict__ WzvT,
                                              const float* __restrict__ bnw,
                                              const float* __restrict__ bnb,
                                              const float* __restrict__ bnm,
                                              const float* __restrict__ bnv,
                                              float* __restrict__ out) {
    __shared__ float sY[C_];
    __shared__ float sP[4][64];
    __shared__ float sZ[64];

    int b = blockIdx.x >> 2;
    int q = blockIdx.x & 3;
    int t = threadIdx.x;

    sY[t] = ysum[b * C_ + t];
    __syncthreads();

    // 4 threads per channel: slice s covers k in [64s, 64s+64)
    int c_local = t & 63;
    int slice   = t >> 6;
    int c       = q * 64 + c_local;
    {
        float acc = 0.f;
        const float* wcol = WzvT + c;           // stride C_ over k
        int k0 = slice * 64;
        #pragma unroll 8
        for (int k = k0; k < k0 + 64; k++)
            acc += sY[k] * wcol[k * C_];        // wave reads 64 consecutive floats (L2-hot)
        sP[slice][c_local] = acc;
    }
    __syncthreads();
    if (t < 64) {
        float z = (sP[0][t] + sP[1][t]) + (sP[2][t] + sP[3][t]);
        int cc = q * 64 + t;
        float alpha = bnw[cc] * rsqrtf(bnv[cc] + EPS);
        sZ[t] = (z - bnm[cc]) * alpha + bnb[cc];
    }
    __syncthreads();

    // Stream the quarter: 3136 float4 = 12*256 + 64
    const float4* xb = (const float4*)x  + (size_t)blockIdx.x * QF4;
    float4*       ob = (float4*)out      + (size_t)blockIdx.x * QF4;
    #pragma unroll
    for (int it = 0; it < 13; it++) {
        int i = it * 256 + t;
        if (i < QF4) {
            float z = sZ[i / NF4];              // broadcast-ish LDS read
            float4 v = xb[i];
            v.x += z; v.y += z; v.z += z; v.w += z;
            ob[i] = v;
        }
    }
}

extern "C" void kernel_launch(void* const* d_in, const int* in_sizes, int n_in,
                              void* d_out, int out_size, void* d_ws, size_t ws_size,
                              hipStream_t stream) {
    const float* x   = (const float*)d_in[0];
    const float* y   = (const float*)d_in[1];
    // d_in[2] = Wq, d_in[3] = Wk : dead code (softmax over singleton axis == 1)
    const float* Wv  = (const float*)d_in[4];
    const float* Wz  = (const float*)d_in[5];
    const float* bnw = (const float*)d_in[6];
    const float* bnb = (const float*)d_in[7];
    const float* bnm = (const float*)d_in[8];
    const float* bnv = (const float*)d_in[9];
    float* out = (float*)d_out;

    float* ysum = (float*)d_ws;                 // 65536 floats
    float* WzvT = ysum + B_ * C_;               // 65536 floats

    // Kernel A: Ysum rows + fused weight product in one dispatch
    k_pre<<<YSUM_BLKS + C_, 256, 0, stream>>>(y, Wz, Wv, ysum, WzvT);
    // Kernel B: per-(b,quarter) Zs + residual broadcast-add epilogue
    k_post<<<B_ * 4, 256, 0, stream>>>(x, ysum, WzvT, bnw, bnb, bnm, bnv, out);
}